// Round 5
// baseline (1805.415 us; speedup 1.0000x reference)
//
#include <hip/hip_runtime.h>
#include <hip/hip_bf16.h>

typedef __hip_bfloat16 bf16;

#define BATCH 128
#define SEQ   200
#define NUMQ  1000
#define DD    64
#define MM    50
#define NT    640   // 10 waves

// at_m is all-ones; second 32-bit word == 0 iff the buffer is int64.
__device__ __forceinline__ bool idx_is64(const void* at_m) {
    return ((const int*)at_m)[1] == 0;
}
__device__ __forceinline__ int load_idx(const void* p, int i, bool is64) {
    return is64 ? (int)((const long long*)p)[i] : ((const int*)p)[i];
}

struct Lds {
    float (*Mk_l)[DD + 1];
    bf16  (*ring)[DD];
    int*   q_row; int* x_row;
    float* kbuf; float* vbuf; float* vbuf2;
    float* wst;  float* est;  float* ast;
    float* partial; float* bias_e; float* bias_a;
};

template<typename T>
__device__ __forceinline__ void body(
    const void* q_, const void* r_, bool is64,
    const T* __restrict__ k_emb, const T* __restrict__ v_emb,
    const T* __restrict__ Mk,    const T* __restrict__ Mv0,
    const T* __restrict__ We,    const T* __restrict__ be,
    const T* __restrict__ Wa,    const T* __restrict__ ba,
    const T* __restrict__ Wf,    const T* __restrict__ bfb,
    const T* __restrict__ Wp,    const T* __restrict__ bp,
    float* __restrict__ out_p, float* __restrict__ out_Mv, Lds L)
{
    const int b    = blockIdx.x;
    const int tid  = threadIdx.x;
    const int wv   = tid >> 6;
    const int lane = tid & 63;

    // ---- stage indices (clamped so garbage can only be finite-wrong) ----
    for (int t = tid; t < SEQ; t += NT) {
        int qi = load_idx(q_, b * SEQ + t, is64);
        int ri = load_idx(r_, b * SEQ + t, is64);
        qi = min(max(qi, 0), NUMQ - 1);
        ri = min(max(ri, 0), 1);
        L.q_row[t] = qi;
        L.x_row[t] = qi + ri * NUMQ;
    }
    for (int i = tid; i < MM * DD; i += NT)
        L.Mk_l[i >> 6][i & 63] = (float)Mk[i];
    if (tid < DD) { L.bias_e[tid] = (float)be[tid]; L.bias_a[tid] = (float)ba[tid]; }

    // ---- Mv state: thread owns (m0..m0+4, d) in registers ----
    const int d  = lane;
    const int m0 = wv * 5;
    float* outb = out_Mv + (size_t)b * (SEQ + 1) * MM * DD;
    float Mv[5];
    #pragma unroll
    for (int j = 0; j < 5; ++j) {
        Mv[j] = (float)Mv0[(m0 + j) * DD + d];
        outb[(m0 + j) * DD + d] = Mv[j];        // Mv[b,0] = Mv0
    }
    __syncthreads();

    // ---- prefetch t=0 gathers ----
    float kf_n = 0.f, vf_n = 0.f, vf2_n = 0.f;
    if (wv == 0) kf_n  = (float)k_emb[(size_t)L.q_row[0] * DD + lane];
    if (wv == 1) vf_n  = (float)v_emb[(size_t)L.x_row[0] * DD + lane];
    if (wv == 2) vf2_n = (float)v_emb[(size_t)L.x_row[0] * DD + lane];

    for (int t = 0; t < SEQ; ++t) {
        // ---- phase A: waves 0/1/2 produce w / e / a ----
        if (wv == 0) {
            L.kbuf[lane] = kf_n;
            if (t + 1 < SEQ) kf_n = (float)k_emb[(size_t)L.q_row[t + 1] * DD + lane];
            float s = 0.f;
            if (lane < MM) {
                #pragma unroll
                for (int dd = 0; dd < DD; ++dd)
                    s += L.kbuf[dd] * L.Mk_l[lane][dd];
            }
            float mx = (lane < MM) ? s : -1e30f;
            #pragma unroll
            for (int off = 32; off >= 1; off >>= 1)
                mx = fmaxf(mx, __shfl_xor(mx, off, 64));
            float ex = (lane < MM) ? expf(s - mx) : 0.f;
            float sm = ex;
            #pragma unroll
            for (int off = 32; off >= 1; off >>= 1)
                sm += __shfl_xor(sm, off, 64);
            if (lane < MM) L.wst[lane] = ex / sm;
        } else if (wv == 1) {
            L.vbuf[lane] = vf_n;
            if (t + 1 < SEQ) vf_n = (float)v_emb[(size_t)L.x_row[t + 1] * DD + lane];
            float acc = L.bias_e[lane];
            #pragma unroll
            for (int dd = 0; dd < DD; ++dd)
                acc += L.vbuf[dd] * (float)We[dd * DD + lane];
            L.est[lane] = 1.f / (1.f + expf(-acc));
        } else if (wv == 2) {
            L.vbuf2[lane] = vf2_n;
            if (t + 1 < SEQ) vf2_n = (float)v_emb[(size_t)L.x_row[t + 1] * DD + lane];
            float acc = L.bias_a[lane];
            #pragma unroll
            for (int dd = 0; dd < DD; ++dd)
                acc += L.vbuf2[dd] * (float)Wa[dd * DD + lane];
            L.ast[lane] = tanhf(acc);
        }
        __syncthreads();   // A: w/e/a staged

        // ---- phase B: all 10 waves update Mv + read partials ----
        const float e_v = L.est[d];
        const float a_v = L.ast[d];
        float racc = 0.f;
        float* outt = outb + (size_t)(t + 1) * MM * DD;
        #pragma unroll
        for (int j = 0; j < 5; ++j) {
            const float wvv = L.wst[m0 + j];
            racc += wvv * Mv[j];                                    // read pre-update
            Mv[j] = __builtin_fmaf(wvv, a_v - e_v * Mv[j], Mv[j]);  // Mv(1-we) + wa
            outt[(m0 + j) * DD + d] = Mv[j];
        }
        L.partial[tid] = racc;
        __syncthreads();   // B: partials ready

        // ---- phase C: wave 0 folds partials into the read-ring ----
        if (tid < DD) {
            float rr = 0.f;
            #pragma unroll
            for (int g = 0; g < 10; ++g) rr += L.partial[g * 64 + tid];
            L.ring[t][tid] = (bf16)rr;
        }
    }
    __syncthreads();

    // ---- final: f = tanh([read,k]@Wf + bf), p = sigmoid(f.Wp + bp) ----
    for (int t = wv; t < SEQ; t += 10) {
        const int qi = L.q_row[t];
        const float kreg = (float)k_emb[(size_t)qi * DD + lane];
        float acc = (float)bfb[lane];
        #pragma unroll
        for (int i = 0; i < DD; ++i)
            acc += (float)L.ring[t][i] * (float)Wf[i * DD + lane];
        #pragma unroll
        for (int i = 0; i < DD; ++i)
            acc += __shfl(kreg, i, 64) * (float)Wf[(DD + i) * DD + lane];
        const float f = tanhf(acc);
        float pv = f * (float)Wp[lane];
        #pragma unroll
        for (int off = 32; off >= 1; off >>= 1)
            pv += __shfl_xor(pv, off, 64);
        if (lane == 0)
            out_p[(size_t)b * SEQ + t] = 1.f / (1.f + expf(-(pv + (float)bp[0])));
    }
}

__global__ __launch_bounds__(NT) void dkvmn_fused(
    const void* q_, const void* r_, const void* at_m,
    const void* k_emb, const void* v_emb, const void* Mk, const void* Mv0,
    const void* We, const void* be, const void* Wa, const void* ba,
    const void* Wf, const void* bfb, const void* Wp, const void* bp,
    float* out_p, float* out_Mv)
{
    __shared__ float Mk_l[MM][DD + 1];
    __shared__ bf16  ring[SEQ][DD];
    __shared__ int   q_row[SEQ], x_row[SEQ];
    __shared__ float kbuf[DD], vbuf[DD], vbuf2[DD];
    __shared__ float wst[MM], est[DD], ast[DD];
    __shared__ float partial[NT];
    __shared__ float bias_e[DD], bias_a[DD];
    __shared__ int   f32flag;

    const int tid = threadIdx.x;
    if (tid == 0) f32flag = 0;
    __syncthreads();

    // Float-width probe: view v_emb as uint16 words; float32 data's mantissa
    // fragments contain exp-all-ones patterns (deterministic for fixed input),
    // valid bf16 normal data never does. 16K words ⊂ buffer in both views.
    bool hit = false;
    const unsigned short* vwp = (const unsigned short*)v_emb;
    for (int i = tid; i < 16384; i += NT)
        hit |= ((vwp[i] & 0x7F80) == 0x7F80);
    if (hit) f32flag = 1;
    __syncthreads();
    const bool isf32 = (f32flag != 0);
    const bool is64  = idx_is64(at_m);

    Lds L{Mk_l, ring, q_row, x_row, kbuf, vbuf, vbuf2, wst, est, ast,
          partial, bias_e, bias_a};

    if (isf32)
        body<float>(q_, r_, is64,
                    (const float*)k_emb, (const float*)v_emb, (const float*)Mk,
                    (const float*)Mv0, (const float*)We, (const float*)be,
                    (const float*)Wa, (const float*)ba, (const float*)Wf,
                    (const float*)bfb, (const float*)Wp, (const float*)bp,
                    out_p, out_Mv, L);
    else
        body<bf16>(q_, r_, is64,
                   (const bf16*)k_emb, (const bf16*)v_emb, (const bf16*)Mk,
                   (const bf16*)Mv0, (const bf16*)We, (const bf16*)be,
                   (const bf16*)Wa, (const bf16*)ba, (const bf16*)Wf,
                   (const bf16*)bfb, (const bf16*)Wp, (const bf16*)bp,
                   out_p, out_Mv, L);
}

extern "C" void kernel_launch(void* const* d_in, const int* in_sizes, int n_in,
                              void* d_out, int out_size, void* d_ws, size_t ws_size,
                              hipStream_t stream) {
    float* out_p  = (float*)d_out;                 // [128,200]
    float* out_Mv = (float*)d_out + BATCH * SEQ;   // [128,201,50,64]

    hipLaunchKernelGGL(dkvmn_fused, dim3(BATCH), dim3(NT), 0, stream,
                       d_in[0], d_in[1], d_in[3],
                       d_in[4], d_in[5], d_in[6], d_in[7],
                       d_in[8], d_in[9], d_in[10], d_in[11],
                       d_in[12], d_in[13], d_in[14], d_in[15],
                       out_p, out_Mv);
}

// Round 6
// 224.019 us; speedup vs baseline: 8.0592x; 8.0592x over previous
//
#include <hip/hip_runtime.h>
#include <hip/hip_bf16.h>

typedef __hip_bfloat16 bf16;

#define BATCH 128
#define SEQ   200
#define NUMQ  1000
#define DD    64
#define MM    50

// Proven by round-5 pass: floats are float32, ints are int32.

__device__ __forceinline__ float rdlane(float v, int j) {
    return __uint_as_float(__builtin_amdgcn_readlane(__float_as_uint(v), j));
}

// ---------------- K1: parallel precompute of w (softmax), e, a over all rows ----------------
__global__ __launch_bounds__(256) void k1_precompute(
    const int* __restrict__ q, const int* __restrict__ r,
    const float* __restrict__ k_emb, const float* __restrict__ v_emb,
    const float* __restrict__ Mk,
    const float* __restrict__ We, const float* __restrict__ be,
    const float* __restrict__ Wa, const float* __restrict__ ba,
    float* __restrict__ w_buf, float* __restrict__ e_buf, float* __restrict__ a_buf)
{
    __shared__ float Mk_l[MM][DD + 1];
    __shared__ float kv_l[4][128];

    const int tid = threadIdx.x;
    for (int i = tid; i < MM * DD; i += 256)
        Mk_l[i >> 6][i & 63] = Mk[i];

    const int w    = tid >> 6;
    const int lane = tid & 63;
    const int row  = blockIdx.x * 4 + w;

    int qi = q[row], ri = r[row];
    qi = min(max(qi, 0), NUMQ - 1);
    ri = min(max(ri, 0), 1);
    const int xi = qi + ri * NUMQ;

    kv_l[w][lane]      = k_emb[(size_t)qi * DD + lane];
    kv_l[w][64 + lane] = v_emb[(size_t)xi * DD + lane];
    __syncthreads();

    float s = 0.f;
    if (lane < MM) {
        #pragma unroll
        for (int dd = 0; dd < DD; ++dd)
            s += kv_l[w][dd] * Mk_l[lane][dd];
    }
    float mx = (lane < MM) ? s : -1e30f;
    #pragma unroll
    for (int off = 32; off >= 1; off >>= 1)
        mx = fmaxf(mx, __shfl_xor(mx, off, 64));
    float ex = (lane < MM) ? expf(s - mx) : 0.f;
    float sm = ex;
    #pragma unroll
    for (int off = 32; off >= 1; off >>= 1)
        sm += __shfl_xor(sm, off, 64);
    if (lane < MM)
        w_buf[(size_t)row * MM + lane] = ex / sm;

    float ea = be[lane], aa = ba[lane];
    #pragma unroll
    for (int dd = 0; dd < DD; ++dd) {
        const float vb = kv_l[w][64 + dd];
        ea = __builtin_fmaf(vb, We[dd * DD + lane], ea);
        aa = __builtin_fmaf(vb, Wa[dd * DD + lane], aa);
    }
    e_buf[(size_t)row * DD + lane] = 1.f / (1.f + expf(-ea));
    a_buf[(size_t)row * DD + lane] = tanhf(aa);
}

// ---------------- K2: barrier-free scan — one wave per batch, lane = d, Mv[50] in VGPRs ----------------
__global__ __launch_bounds__(64) void k2_scan_wave(
    const float* __restrict__ Mv0,
    const float* __restrict__ w_buf, const float* __restrict__ e_buf,
    const float* __restrict__ a_buf,
    float* __restrict__ read_buf, float* __restrict__ out_Mv)
{
    const int b    = blockIdx.x;
    const int lane = threadIdx.x;    // = d

    float Mv[MM];
    float* outb = out_Mv + (size_t)b * (SEQ + 1) * MM * DD;
    #pragma unroll
    for (int j = 0; j < MM; ++j) {
        Mv[j] = Mv0[j * DD + lane];
        outb[j * DD + lane] = Mv[j];          // Mv[b,0] = Mv0
    }

    const float* wrow = w_buf + (size_t)b * SEQ * MM;
    const float* erow = e_buf + (size_t)b * SEQ * DD;
    const float* arow = a_buf + (size_t)b * SEQ * DD;
    float*       rrow = read_buf + (size_t)b * SEQ * DD;

    // prefetch t=0
    float wreg = (lane < MM) ? wrow[lane] : 0.f;
    float e_n  = erow[lane];
    float a_n  = arow[lane];

    for (int t = 0; t < SEQ; ++t) {
        const float e_v = e_n, a_v = a_n;
        const float wcur = wreg;
        if (t + 1 < SEQ) {                    // prefetch next step (hides L2/HBM latency)
            wreg = (lane < MM) ? wrow[(size_t)(t + 1) * MM + lane] : 0.f;
            e_n  = erow[(size_t)(t + 1) * DD + lane];
            a_n  = arow[(size_t)(t + 1) * DD + lane];
        }
        float* outt = outb + (size_t)(t + 1) * MM * DD;
        float racc0 = 0.f, racc1 = 0.f;
        #pragma unroll
        for (int j = 0; j < MM; ++j) {
            const float wj    = rdlane(wcur, j);            // wave-uniform SGPR scalar
            const float m_old = Mv[j];
            if (j & 1) racc1 = __builtin_fmaf(wj, m_old, racc1);
            else       racc0 = __builtin_fmaf(wj, m_old, racc0);
            Mv[j] = __builtin_fmaf(wj, __builtin_fmaf(-e_v, m_old, a_v), m_old);
            outt[j * DD + lane] = Mv[j];      // fire-and-forget, no barrier anywhere
        }
        rrow[(size_t)t * DD + lane] = racc0 + racc1;
    }
}

// ---------------- K3: f = tanh([read,k]@Wf+bf), p = sigmoid(f.Wp+bp) ----------------
__global__ __launch_bounds__(256) void k3_out(
    const int* __restrict__ q,
    const float* __restrict__ k_emb,
    const float* __restrict__ read_buf,
    const float* __restrict__ Wf, const float* __restrict__ bfb,
    const float* __restrict__ Wp, const float* __restrict__ bp,
    float* __restrict__ out_p)
{
    __shared__ float rk[4][128];
    const int tid  = threadIdx.x;
    const int w    = tid >> 6;
    const int lane = tid & 63;
    const int row  = blockIdx.x * 4 + w;

    int qi = q[row];
    qi = min(max(qi, 0), NUMQ - 1);
    rk[w][lane]      = read_buf[(size_t)row * DD + lane];
    rk[w][64 + lane] = k_emb[(size_t)qi * DD + lane];
    __syncthreads();

    float acc = bfb[lane];
    #pragma unroll
    for (int i = 0; i < 2 * DD; ++i)
        acc = __builtin_fmaf(rk[w][i], Wf[i * DD + lane], acc);
    const float f = tanhf(acc);

    float pv = f * Wp[lane];
    #pragma unroll
    for (int off = 32; off >= 1; off >>= 1)
        pv += __shfl_xor(pv, off, 64);

    if (lane == 0)
        out_p[row] = 1.f / (1.f + expf(-(pv + bp[0])));
}

// ---------------- Fallback: round-5 fused kernel (proven), used only if ws is too small ----------------
struct Lds {
    float (*Mk_l)[DD + 1];
    bf16  (*ring)[DD];
    int*   q_row; int* x_row;
    float* kbuf; float* vbuf; float* vbuf2;
    float* wst;  float* est;  float* ast;
    float* partial; float* bias_e; float* bias_a;
};

__global__ __launch_bounds__(640) void dkvmn_fused(
    const int* q_, const int* r_,
    const float* k_emb, const float* v_emb, const float* Mk, const float* Mv0,
    const float* We, const float* be, const float* Wa, const float* ba,
    const float* Wf, const float* bfb, const float* Wp, const float* bp,
    float* out_p, float* out_Mv)
{
    __shared__ float Mk_l[MM][DD + 1];
    __shared__ bf16  ring[SEQ][DD];
    __shared__ int   q_row[SEQ], x_row[SEQ];
    __shared__ float kbuf[DD], vbuf[DD], vbuf2[DD];
    __shared__ float wst[MM], est[DD], ast[DD];
    __shared__ float partial[640];
    __shared__ float bias_e[DD], bias_a[DD];

    const int b    = blockIdx.x;
    const int tid  = threadIdx.x;
    const int wv   = tid >> 6;
    const int lane = tid & 63;

    for (int t = tid; t < SEQ; t += 640) {
        int qi = q_[b * SEQ + t], ri = r_[b * SEQ + t];
        qi = min(max(qi, 0), NUMQ - 1); ri = min(max(ri, 0), 1);
        q_row[t] = qi; x_row[t] = qi + ri * NUMQ;
    }
    for (int i = tid; i < MM * DD; i += 640) Mk_l[i >> 6][i & 63] = Mk[i];
    if (tid < DD) { bias_e[tid] = be[tid]; bias_a[tid] = ba[tid]; }

    const int d  = lane;
    const int m0 = wv * 5;
    float* outb = out_Mv + (size_t)b * (SEQ + 1) * MM * DD;
    float Mv[5];
    #pragma unroll
    for (int j = 0; j < 5; ++j) {
        Mv[j] = Mv0[(m0 + j) * DD + d];
        outb[(m0 + j) * DD + d] = Mv[j];
    }
    __syncthreads();

    float kf_n = 0.f, vf_n = 0.f, vf2_n = 0.f;
    if (wv == 0) kf_n  = k_emb[(size_t)q_row[0] * DD + lane];
    if (wv == 1) vf_n  = v_emb[(size_t)x_row[0] * DD + lane];
    if (wv == 2) vf2_n = v_emb[(size_t)x_row[0] * DD + lane];

    for (int t = 0; t < SEQ; ++t) {
        if (wv == 0) {
            kbuf[lane] = kf_n;
            if (t + 1 < SEQ) kf_n = k_emb[(size_t)q_row[t + 1] * DD + lane];
            float s = 0.f;
            if (lane < MM) {
                #pragma unroll
                for (int dd = 0; dd < DD; ++dd) s += kbuf[dd] * Mk_l[lane][dd];
            }
            float mx = (lane < MM) ? s : -1e30f;
            #pragma unroll
            for (int off = 32; off >= 1; off >>= 1) mx = fmaxf(mx, __shfl_xor(mx, off, 64));
            float ex = (lane < MM) ? expf(s - mx) : 0.f;
            float sm = ex;
            #pragma unroll
            for (int off = 32; off >= 1; off >>= 1) sm += __shfl_xor(sm, off, 64);
            if (lane < MM) wst[lane] = ex / sm;
        } else if (wv == 1) {
            vbuf[lane] = vf_n;
            if (t + 1 < SEQ) vf_n = v_emb[(size_t)x_row[t + 1] * DD + lane];
            float acc = bias_e[lane];
            #pragma unroll
            for (int dd = 0; dd < DD; ++dd) acc += vbuf[dd] * We[dd * DD + lane];
            est[lane] = 1.f / (1.f + expf(-acc));
        } else if (wv == 2) {
            vbuf2[lane] = vf2_n;
            if (t + 1 < SEQ) vf2_n = v_emb[(size_t)x_row[t + 1] * DD + lane];
            float acc = bias_a[lane];
            #pragma unroll
            for (int dd = 0; dd < DD; ++dd) acc += vbuf2[dd] * Wa[dd * DD + lane];
            ast[lane] = tanhf(acc);
        }
        __syncthreads();

        const float e_v = est[d];
        const float a_v = ast[d];
        float racc = 0.f;
        float* outt = outb + (size_t)(t + 1) * MM * DD;
        #pragma unroll
        for (int j = 0; j < 5; ++j) {
            const float wvv = wst[m0 + j];
            racc += wvv * Mv[j];
            Mv[j] = __builtin_fmaf(wvv, a_v - e_v * Mv[j], Mv[j]);
            outt[(m0 + j) * DD + d] = Mv[j];
        }
        partial[tid] = racc;
        __syncthreads();

        if (tid < DD) {
            float rr = 0.f;
            #pragma unroll
            for (int g = 0; g < 10; ++g) rr += partial[g * 64 + tid];
            ring[t][tid] = (bf16)rr;
        }
    }
    __syncthreads();

    for (int t = wv; t < SEQ; t += 10) {
        const int qi = q_row[t];
        const float kreg = k_emb[(size_t)qi * DD + lane];
        float acc = bfb[lane];
        #pragma unroll
        for (int i = 0; i < DD; ++i) acc += (float)ring[t][i] * Wf[i * DD + lane];
        #pragma unroll
        for (int i = 0; i < DD; ++i) acc += __shfl(kreg, i, 64) * Wf[(DD + i) * DD + lane];
        const float f = tanhf(acc);
        float pv = f * Wp[lane];
        #pragma unroll
        for (int off = 32; off >= 1; off >>= 1) pv += __shfl_xor(pv, off, 64);
        if (lane == 0)
            out_p[(size_t)b * SEQ + t] = 1.f / (1.f + expf(-(pv + bp[0])));
    }
}

extern "C" void kernel_launch(void* const* d_in, const int* in_sizes, int n_in,
                              void* d_out, int out_size, void* d_ws, size_t ws_size,
                              hipStream_t stream) {
    const int*   q     = (const int*)  d_in[0];
    const int*   r     = (const int*)  d_in[1];
    const float* k_emb = (const float*)d_in[4];
    const float* v_emb = (const float*)d_in[5];
    const float* Mk    = (const float*)d_in[6];
    const float* Mv0   = (const float*)d_in[7];
    const float* We    = (const float*)d_in[8];
    const float* be    = (const float*)d_in[9];
    const float* Wa    = (const float*)d_in[10];
    const float* ba    = (const float*)d_in[11];
    const float* Wf    = (const float*)d_in[12];
    const float* bfb   = (const float*)d_in[13];
    const float* Wp    = (const float*)d_in[14];
    const float* bp    = (const float*)d_in[15];

    float* out_p  = (float*)d_out;                 // [128,200]
    float* out_Mv = (float*)d_out + BATCH * SEQ;   // [128,201,50,64]

    const size_t WS_NEEDED = (size_t)BATCH * SEQ * (MM + 3 * DD) * sizeof(float);

    if (ws_size >= WS_NEEDED) {
        float* w_buf    = (float*)d_ws;                          // [B,SEQ,50]
        float* e_buf    = w_buf + (size_t)BATCH * SEQ * MM;      // [B,SEQ,64]
        float* a_buf    = e_buf + (size_t)BATCH * SEQ * DD;      // [B,SEQ,64]
        float* read_buf = a_buf + (size_t)BATCH * SEQ * DD;      // [B,SEQ,64]

        const int rows = BATCH * SEQ;

        hipLaunchKernelGGL(k1_precompute, dim3(rows / 4), dim3(256), 0, stream,
                           q, r, k_emb, v_emb, Mk, We, be, Wa, ba, w_buf, e_buf, a_buf);
        hipLaunchKernelGGL(k2_scan_wave, dim3(BATCH), dim3(64), 0, stream,
                           Mv0, w_buf, e_buf, a_buf, read_buf, out_Mv);
        hipLaunchKernelGGL(k3_out, dim3(rows / 4), dim3(256), 0, stream,
                           q, k_emb, read_buf, Wf, bfb, Wp, bp, out_p);
    } else {
        hipLaunchKernelGGL(dkvmn_fused, dim3(BATCH), dim3(640), 0, stream,
                           q, r, k_emb, v_emb, Mk, Mv0, We, be, Wa, ba,
                           Wf, bfb, Wp, bp, out_p, out_Mv);
    }
}

// Round 7
// 189.839 us; speedup vs baseline: 9.5102x; 1.1800x over previous
//
#include <hip/hip_runtime.h>
#include <hip/hip_bf16.h>

typedef __hip_bfloat16 bf16;

#define BATCH 128
#define SEQ   200
#define NUMQ  1000
#define DD    64
#define MM    50
#define CHUNKS 10
#define CLEN   20   // SEQ / CHUNKS

// Proven by round-5/6 passes: floats are float32, ints are int32.

__device__ __forceinline__ float rdlane(float v, int j) {
    return __uint_as_float(__builtin_amdgcn_readlane(__float_as_uint(v), j));
}

// ---------------- K1: parallel precompute of w (softmax), e, a over all rows ----------------
__global__ __launch_bounds__(256) void k1_precompute(
    const int* __restrict__ q, const int* __restrict__ r,
    const float* __restrict__ k_emb, const float* __restrict__ v_emb,
    const float* __restrict__ Mk,
    const float* __restrict__ We, const float* __restrict__ be,
    const float* __restrict__ Wa, const float* __restrict__ ba,
    float* __restrict__ w_buf, float* __restrict__ e_buf, float* __restrict__ a_buf)
{
    __shared__ float Mk_l[MM][DD + 1];
    __shared__ float kv_l[4][128];

    const int tid = threadIdx.x;
    for (int i = tid; i < MM * DD; i += 256)
        Mk_l[i >> 6][i & 63] = Mk[i];

    const int w    = tid >> 6;
    const int lane = tid & 63;
    const int row  = blockIdx.x * 4 + w;

    int qi = q[row], ri = r[row];
    qi = min(max(qi, 0), NUMQ - 1);
    ri = min(max(ri, 0), 1);
    const int xi = qi + ri * NUMQ;

    kv_l[w][lane]      = k_emb[(size_t)qi * DD + lane];
    kv_l[w][64 + lane] = v_emb[(size_t)xi * DD + lane];
    __syncthreads();

    float s = 0.f;
    if (lane < MM) {
        #pragma unroll
        for (int dd = 0; dd < DD; ++dd)
            s += kv_l[w][dd] * Mk_l[lane][dd];
    }
    float mx = (lane < MM) ? s : -1e30f;
    #pragma unroll
    for (int off = 32; off >= 1; off >>= 1)
        mx = fmaxf(mx, __shfl_xor(mx, off, 64));
    float ex = (lane < MM) ? expf(s - mx) : 0.f;
    float sm = ex;
    #pragma unroll
    for (int off = 32; off >= 1; off >>= 1)
        sm += __shfl_xor(sm, off, 64);
    if (lane < MM)
        w_buf[(size_t)row * MM + lane] = ex / sm;

    float ea = be[lane], aa = ba[lane];
    #pragma unroll
    for (int dd = 0; dd < DD; ++dd) {
        const float vb = kv_l[w][64 + dd];
        ea = __builtin_fmaf(vb, We[dd * DD + lane], ea);
        aa = __builtin_fmaf(vb, Wa[dd * DD + lane], aa);
    }
    e_buf[(size_t)row * DD + lane] = 1.f / (1.f + expf(-ea));
    a_buf[(size_t)row * DD + lane] = tanhf(aa);
}

// ---------------- K2: chunked scan — block (b,c) dry-runs t<c*CLEN, stores its chunk ----------------
__global__ __launch_bounds__(64) void k2_scan_chunked(
    const float* __restrict__ Mv0,
    const float* __restrict__ w_buf, const float* __restrict__ e_buf,
    const float* __restrict__ a_buf,
    float* __restrict__ read_buf, float* __restrict__ out_Mv)
{
    const int bid  = blockIdx.x;
    const int b    = bid / CHUNKS;
    const int c    = bid % CHUNKS;       // same-b chunks adjacent -> spread across XCDs; L3 holds w/e/a
    const int lane = threadIdx.x;        // = d
    const int t0   = c * CLEN;

    float Mv[MM];
    float* outb = out_Mv + (size_t)b * (SEQ + 1) * MM * DD;
    #pragma unroll
    for (int j = 0; j < MM; ++j)
        Mv[j] = Mv0[j * DD + lane];
    if (c == 0) {
        #pragma unroll
        for (int j = 0; j < MM; ++j)
            outb[j * DD + lane] = Mv[j];          // Mv[b,0] = Mv0
    }

    const float* wrow = w_buf + (size_t)b * SEQ * MM;
    const float* erow = e_buf + (size_t)b * SEQ * DD;
    const float* arow = a_buf + (size_t)b * SEQ * DD;
    float*       rrow = read_buf + (size_t)b * SEQ * DD;

    // prefetch t=0
    float wreg = (lane < MM) ? wrow[lane] : 0.f;
    float e_n  = erow[lane];
    float a_n  = arow[lane];

    // ---- dry phase: advance state through t in [0, t0); update-only, no stores ----
    for (int t = 0; t < t0; ++t) {
        const float e_v = e_n, a_v = a_n, wcur = wreg;
        wreg = (lane < MM) ? wrow[(size_t)(t + 1) * MM + lane] : 0.f;   // t+1 <= t0 < SEQ
        e_n  = erow[(size_t)(t + 1) * DD + lane];
        a_n  = arow[(size_t)(t + 1) * DD + lane];
        #pragma unroll
        for (int j = 0; j < MM; ++j) {
            const float wj = rdlane(wcur, j);
            Mv[j] = __builtin_fmaf(wj, __builtin_fmaf(-e_v, Mv[j], a_v), Mv[j]);
        }
    }

    // ---- real phase: t in [t0, t0+CLEN); store Mv_{t+1} and read_t ----
    for (int tt = 0; tt < CLEN; ++tt) {
        const int t = t0 + tt;
        const float e_v = e_n, a_v = a_n, wcur = wreg;
        if (t + 1 < SEQ) {                         // harmless over-prefetch past chunk end
            wreg = (lane < MM) ? wrow[(size_t)(t + 1) * MM + lane] : 0.f;
            e_n  = erow[(size_t)(t + 1) * DD + lane];
            a_n  = arow[(size_t)(t + 1) * DD + lane];
        }
        float* outt = outb + (size_t)(t + 1) * MM * DD;
        float racc0 = 0.f, racc1 = 0.f;
        #pragma unroll
        for (int j = 0; j < MM; ++j) {
            const float wj    = rdlane(wcur, j);
            const float m_old = Mv[j];
            if (j & 1) racc1 = __builtin_fmaf(wj, m_old, racc1);
            else       racc0 = __builtin_fmaf(wj, m_old, racc0);
            Mv[j] = __builtin_fmaf(wj, __builtin_fmaf(-e_v, m_old, a_v), m_old);
            outt[j * DD + lane] = Mv[j];           // fire-and-forget
        }
        rrow[(size_t)t * DD + lane] = racc0 + racc1;
    }
}

// ---------------- K3: f = tanh([read,k]@Wf+bf), p = sigmoid(f.Wp+bp) ----------------
__global__ __launch_bounds__(256) void k3_out(
    const int* __restrict__ q,
    const float* __restrict__ k_emb,
    const float* __restrict__ read_buf,
    const float* __restrict__ Wf, const float* __restrict__ bfb,
    const float* __restrict__ Wp, const float* __restrict__ bp,
    float* __restrict__ out_p)
{
    __shared__ float rk[4][128];
    const int tid  = threadIdx.x;
    const int w    = tid >> 6;
    const int lane = tid & 63;
    const int row  = blockIdx.x * 4 + w;

    int qi = q[row];
    qi = min(max(qi, 0), NUMQ - 1);
    rk[w][lane]      = read_buf[(size_t)row * DD + lane];
    rk[w][64 + lane] = k_emb[(size_t)qi * DD + lane];
    __syncthreads();

    float acc = bfb[lane];
    #pragma unroll
    for (int i = 0; i < 2 * DD; ++i)
        acc = __builtin_fmaf(rk[w][i], Wf[i * DD + lane], acc);
    const float f = tanhf(acc);

    float pv = f * Wp[lane];
    #pragma unroll
    for (int off = 32; off >= 1; off >>= 1)
        pv += __shfl_xor(pv, off, 64);

    if (lane == 0)
        out_p[row] = 1.f / (1.f + expf(-(pv + bp[0])));
}

// ---------------- Fallback: round-5 fused kernel (proven), used only if ws is too small ----------------
__global__ __launch_bounds__(640) void dkvmn_fused(
    const int* q_, const int* r_,
    const float* k_emb, const float* v_emb, const float* Mk, const float* Mv0,
    const float* We, const float* be, const float* Wa, const float* ba,
    const float* Wf, const float* bfb, const float* Wp, const float* bp,
    float* out_p, float* out_Mv)
{
    __shared__ float Mk_l[MM][DD + 1];
    __shared__ bf16  ring[SEQ][DD];
    __shared__ int   q_row[SEQ], x_row[SEQ];
    __shared__ float kbuf[DD], vbuf[DD], vbuf2[DD];
    __shared__ float wst[MM], est[DD], ast[DD];
    __shared__ float partial[640];
    __shared__ float bias_e[DD], bias_a[DD];

    const int b    = blockIdx.x;
    const int tid  = threadIdx.x;
    const int wv   = tid >> 6;
    const int lane = tid & 63;

    for (int t = tid; t < SEQ; t += 640) {
        int qi = q_[b * SEQ + t], ri = r_[b * SEQ + t];
        qi = min(max(qi, 0), NUMQ - 1); ri = min(max(ri, 0), 1);
        q_row[t] = qi; x_row[t] = qi + ri * NUMQ;
    }
    for (int i = tid; i < MM * DD; i += 640) Mk_l[i >> 6][i & 63] = Mk[i];
    if (tid < DD) { bias_e[tid] = be[tid]; bias_a[tid] = ba[tid]; }

    const int d  = lane;
    const int m0 = wv * 5;
    float* outb = out_Mv + (size_t)b * (SEQ + 1) * MM * DD;
    float Mv[5];
    #pragma unroll
    for (int j = 0; j < 5; ++j) {
        Mv[j] = Mv0[(m0 + j) * DD + d];
        outb[(m0 + j) * DD + d] = Mv[j];
    }
    __syncthreads();

    float kf_n = 0.f, vf_n = 0.f, vf2_n = 0.f;
    if (wv == 0) kf_n  = k_emb[(size_t)q_row[0] * DD + lane];
    if (wv == 1) vf_n  = v_emb[(size_t)x_row[0] * DD + lane];
    if (wv == 2) vf2_n = v_emb[(size_t)x_row[0] * DD + lane];

    for (int t = 0; t < SEQ; ++t) {
        if (wv == 0) {
            kbuf[lane] = kf_n;
            if (t + 1 < SEQ) kf_n = k_emb[(size_t)q_row[t + 1] * DD + lane];
            float s = 0.f;
            if (lane < MM) {
                #pragma unroll
                for (int dd = 0; dd < DD; ++dd) s += kbuf[dd] * Mk_l[lane][dd];
            }
            float mx = (lane < MM) ? s : -1e30f;
            #pragma unroll
            for (int off = 32; off >= 1; off >>= 1) mx = fmaxf(mx, __shfl_xor(mx, off, 64));
            float ex = (lane < MM) ? expf(s - mx) : 0.f;
            float sm = ex;
            #pragma unroll
            for (int off = 32; off >= 1; off >>= 1) sm += __shfl_xor(sm, off, 64);
            if (lane < MM) wst[lane] = ex / sm;
        } else if (wv == 1) {
            vbuf[lane] = vf_n;
            if (t + 1 < SEQ) vf_n = v_emb[(size_t)x_row[t + 1] * DD + lane];
            float acc = bias_e[lane];
            #pragma unroll
            for (int dd = 0; dd < DD; ++dd) acc += vbuf[dd] * We[dd * DD + lane];
            est[lane] = 1.f / (1.f + expf(-acc));
        } else if (wv == 2) {
            vbuf2[lane] = vf2_n;
            if (t + 1 < SEQ) vf2_n = v_emb[(size_t)x_row[t + 1] * DD + lane];
            float acc = bias_a[lane];
            #pragma unroll
            for (int dd = 0; dd < DD; ++dd) acc += vbuf2[dd] * Wa[dd * DD + lane];
            ast[lane] = tanhf(acc);
        }
        __syncthreads();

        const float e_v = est[d];
        const float a_v = ast[d];
        float racc = 0.f;
        float* outt = outb + (size_t)(t + 1) * MM * DD;
        #pragma unroll
        for (int j = 0; j < 5; ++j) {
            const float wvv = wst[m0 + j];
            racc += wvv * Mv[j];
            Mv[j] = __builtin_fmaf(wvv, a_v - e_v * Mv[j], Mv[j]);
            outt[(m0 + j) * DD + d] = Mv[j];
        }
        partial[tid] = racc;
        __syncthreads();

        if (tid < DD) {
            float rr = 0.f;
            #pragma unroll
            for (int g = 0; g < 10; ++g) rr += partial[g * 64 + tid];
            ring[t][tid] = (bf16)rr;
        }
    }
    __syncthreads();

    for (int t = wv; t < SEQ; t += 10) {
        const int qi = q_row[t];
        const float kreg = k_emb[(size_t)qi * DD + lane];
        float acc = bfb[lane];
        #pragma unroll
        for (int i = 0; i < DD; ++i) acc += (float)ring[t][i] * Wf[i * DD + lane];
        #pragma unroll
        for (int i = 0; i < DD; ++i) acc += __shfl(kreg, i, 64) * Wf[(DD + i) * DD + lane];
        const float f = tanhf(acc);
        float pv = f * Wp[lane];
        #pragma unroll
        for (int off = 32; off >= 1; off >>= 1) pv += __shfl_xor(pv, off, 64);
        if (lane == 0)
            out_p[(size_t)b * SEQ + t] = 1.f / (1.f + expf(-(pv + bp[0])));
    }
}

extern "C" void kernel_launch(void* const* d_in, const int* in_sizes, int n_in,
                              void* d_out, int out_size, void* d_ws, size_t ws_size,
                              hipStream_t stream) {
    const int*   q     = (const int*)  d_in[0];
    const int*   r     = (const int*)  d_in[1];
    const float* k_emb = (const float*)d_in[4];
    const float* v_emb = (const float*)d_in[5];
    const float* Mk    = (const float*)d_in[6];
    const float* Mv0   = (const float*)d_in[7];
    const float* We    = (const float*)d_in[8];
    const float* be    = (const float*)d_in[9];
    const float* Wa    = (const float*)d_in[10];
    const float* ba    = (const float*)d_in[11];
    const float* Wf    = (const float*)d_in[12];
    const float* bfb   = (const float*)d_in[13];
    const float* Wp    = (const float*)d_in[14];
    const float* bp    = (const float*)d_in[15];

    float* out_p  = (float*)d_out;                 // [128,200]
    float* out_Mv = (float*)d_out + BATCH * SEQ;   // [128,201,50,64]

    const size_t WS_NEEDED = (size_t)BATCH * SEQ * (MM + 3 * DD) * sizeof(float);

    if (ws_size >= WS_NEEDED) {
        float* w_buf    = (float*)d_ws;                          // [B,SEQ,50]
        float* e_buf    = w_buf + (size_t)BATCH * SEQ * MM;      // [B,SEQ,64]
        float* a_buf    = e_buf + (size_t)BATCH * SEQ * DD;      // [B,SEQ,64]
        float* read_buf = a_buf + (size_t)BATCH * SEQ * DD;      // [B,SEQ,64]

        const int rows = BATCH * SEQ;

        hipLaunchKernelGGL(k1_precompute, dim3(rows / 4), dim3(256), 0, stream,
                           q, r, k_emb, v_emb, Mk, We, be, Wa, ba, w_buf, e_buf, a_buf);
        hipLaunchKernelGGL(k2_scan_chunked, dim3(BATCH * CHUNKS), dim3(64), 0, stream,
                           Mv0, w_buf, e_buf, a_buf, read_buf, out_Mv);
        hipLaunchKernelGGL(k3_out, dim3(rows / 4), dim3(256), 0, stream,
                           q, k_emb, read_buf, Wf, bfb, Wp, bp, out_p);
    } else {
        hipLaunchKernelGGL(dkvmn_fused, dim3(BATCH), dim3(640), 0, stream,
                           q, r, k_emb, v_emb, Mk, Mv0, We, be, Wa, ba,
                           Wf, bfb, Wp, bp, out_p, out_Mv);
    }
}

// Round 8
// 184.045 us; speedup vs baseline: 9.8096x; 1.0315x over previous
//
#include <hip/hip_runtime.h>
#include <hip/hip_bf16.h>

typedef __hip_bfloat16 bf16;

#define BATCH 128
#define SEQ   200
#define NUMQ  1000
#define DD    64
#define MM    50
#define CHUNKS 10
#define CLEN   20   // SEQ / CHUNKS

// Proven by round-5/6/7 passes: floats are float32, ints are int32.

__device__ __forceinline__ float rdlane(float v, int j) {
    return __uint_as_float(__builtin_amdgcn_readlane(__float_as_uint(v), j));
}

// ---------------- K1: parallel precompute of w (softmax), e, a over all rows ----------------
__global__ __launch_bounds__(256) void k1_precompute(
    const int* __restrict__ q, const int* __restrict__ r,
    const float* __restrict__ k_emb, const float* __restrict__ v_emb,
    const float* __restrict__ Mk,
    const float* __restrict__ We, const float* __restrict__ be,
    const float* __restrict__ Wa, const float* __restrict__ ba,
    float* __restrict__ w_buf, float* __restrict__ e_buf, float* __restrict__ a_buf)
{
    __shared__ float Mk_l[MM][DD + 1];
    __shared__ float kv_l[4][128];

    const int tid = threadIdx.x;
    for (int i = tid; i < MM * DD; i += 256)
        Mk_l[i >> 6][i & 63] = Mk[i];

    const int w    = tid >> 6;
    const int lane = tid & 63;
    const int row  = blockIdx.x * 4 + w;

    int qi = q[row], ri = r[row];
    qi = min(max(qi, 0), NUMQ - 1);
    ri = min(max(ri, 0), 1);
    const int xi = qi + ri * NUMQ;

    kv_l[w][lane]      = k_emb[(size_t)qi * DD + lane];
    kv_l[w][64 + lane] = v_emb[(size_t)xi * DD + lane];
    __syncthreads();

    float s = 0.f;
    if (lane < MM) {
        #pragma unroll
        for (int dd = 0; dd < DD; ++dd)
            s += kv_l[w][dd] * Mk_l[lane][dd];
    }
    float mx = (lane < MM) ? s : -1e30f;
    #pragma unroll
    for (int off = 32; off >= 1; off >>= 1)
        mx = fmaxf(mx, __shfl_xor(mx, off, 64));
    float ex = (lane < MM) ? expf(s - mx) : 0.f;
    float sm = ex;
    #pragma unroll
    for (int off = 32; off >= 1; off >>= 1)
        sm += __shfl_xor(sm, off, 64);
    if (lane < MM)
        w_buf[(size_t)row * MM + lane] = ex / sm;

    float ea = be[lane], aa = ba[lane];
    #pragma unroll
    for (int dd = 0; dd < DD; ++dd) {
        const float vb = kv_l[w][64 + dd];
        ea = __builtin_fmaf(vb, We[dd * DD + lane], ea);
        aa = __builtin_fmaf(vb, Wa[dd * DD + lane], aa);
    }
    e_buf[(size_t)row * DD + lane] = 1.f / (1.f + expf(-ea));
    a_buf[(size_t)row * DD + lane] = tanhf(aa);
}

// ---------------- K2a: per-chunk affine summary  E_out = A ⊙ E_in + B ----------------
// Per cell (m,d) per step: f = 1 - w_m e_d, g = w_m a_d;  A *= f;  B = f*B + g.
__global__ __launch_bounds__(64) void k2a_summary(
    const float* __restrict__ w_buf, const float* __restrict__ e_buf,
    const float* __restrict__ a_buf,
    float* __restrict__ Abuf, float* __restrict__ Bbuf)
{
    const int bid  = blockIdx.x;
    const int b    = bid / CHUNKS;
    const int c    = bid % CHUNKS;
    const int lane = threadIdx.x;   // = d
    const int t0   = c * CLEN;

    const float* wrow = w_buf + (size_t)b * SEQ * MM;
    const float* erow = e_buf + (size_t)b * SEQ * DD;
    const float* arow = a_buf + (size_t)b * SEQ * DD;

    float A[MM], B[MM];
    #pragma unroll
    for (int j = 0; j < MM; ++j) { A[j] = 1.f; B[j] = 0.f; }

    float wreg = (lane < MM) ? wrow[(size_t)t0 * MM + lane] : 0.f;
    float e_n  = erow[(size_t)t0 * DD + lane];
    float a_n  = arow[(size_t)t0 * DD + lane];

    for (int tt = 0; tt < CLEN; ++tt) {
        const int t = t0 + tt;
        const float e_v = e_n, a_v = a_n, wcur = wreg;
        if (t + 1 < SEQ) {
            wreg = (lane < MM) ? wrow[(size_t)(t + 1) * MM + lane] : 0.f;
            e_n  = erow[(size_t)(t + 1) * DD + lane];
            a_n  = arow[(size_t)(t + 1) * DD + lane];
        }
        #pragma unroll
        for (int j = 0; j < MM; ++j) {
            const float wj = rdlane(wcur, j);
            const float f  = __builtin_fmaf(-wj, e_v, 1.f);
            const float g  = wj * a_v;
            A[j] *= f;
            B[j] = __builtin_fmaf(B[j], f, g);
        }
    }

    float* Ao = Abuf + ((size_t)bid * MM) * DD;
    float* Bo = Bbuf + ((size_t)bid * MM) * DD;
    #pragma unroll
    for (int j = 0; j < MM; ++j) {
        Ao[j * DD + lane] = A[j];
        Bo[j * DD + lane] = B[j];
    }
}

// ---------------- K2c: reconstruct entry state from summaries, replay chunk with stores ----------------
__global__ __launch_bounds__(64) void k2c_replay(
    const float* __restrict__ Mv0,
    const float* __restrict__ w_buf, const float* __restrict__ e_buf,
    const float* __restrict__ a_buf,
    const float* __restrict__ Abuf, const float* __restrict__ Bbuf,
    float* __restrict__ read_buf, float* __restrict__ out_Mv)
{
    const int bid  = blockIdx.x;
    const int b    = bid / CHUNKS;
    const int c    = bid % CHUNKS;
    const int lane = threadIdx.x;   // = d
    const int t0   = c * CLEN;

    float Mv[MM];
    float* outb = out_Mv + (size_t)b * (SEQ + 1) * MM * DD;
    #pragma unroll
    for (int j = 0; j < MM; ++j)
        Mv[j] = Mv0[j * DD + lane];
    if (c == 0) {
        #pragma unroll
        for (int j = 0; j < MM; ++j)
            outb[j * DD + lane] = Mv[j];          // Mv[b,0] = Mv0
    }

    // combine prior chunk summaries: E = A_cc ⊙ E + B_cc, cc = 0..c-1
    for (int cc = 0; cc < c; ++cc) {
        const float* Ao = Abuf + ((size_t)(b * CHUNKS + cc) * MM) * DD;
        const float* Bo = Bbuf + ((size_t)(b * CHUNKS + cc) * MM) * DD;
        #pragma unroll
        for (int j = 0; j < MM; ++j)
            Mv[j] = __builtin_fmaf(Ao[j * DD + lane], Mv[j], Bo[j * DD + lane]);
    }

    const float* wrow = w_buf + (size_t)b * SEQ * MM;
    const float* erow = e_buf + (size_t)b * SEQ * DD;
    const float* arow = a_buf + (size_t)b * SEQ * DD;
    float*       rrow = read_buf + (size_t)b * SEQ * DD;

    float wreg = (lane < MM) ? wrow[(size_t)t0 * MM + lane] : 0.f;
    float e_n  = erow[(size_t)t0 * DD + lane];
    float a_n  = arow[(size_t)t0 * DD + lane];

    for (int tt = 0; tt < CLEN; ++tt) {
        const int t = t0 + tt;
        const float e_v = e_n, a_v = a_n, wcur = wreg;
        if (t + 1 < SEQ) {
            wreg = (lane < MM) ? wrow[(size_t)(t + 1) * MM + lane] : 0.f;
            e_n  = erow[(size_t)(t + 1) * DD + lane];
            a_n  = arow[(size_t)(t + 1) * DD + lane];
        }
        float* outt = outb + (size_t)(t + 1) * MM * DD;
        float racc0 = 0.f, racc1 = 0.f;
        #pragma unroll
        for (int j = 0; j < MM; ++j) {
            const float wj    = rdlane(wcur, j);
            const float m_old = Mv[j];
            if (j & 1) racc1 = __builtin_fmaf(wj, m_old, racc1);
            else       racc0 = __builtin_fmaf(wj, m_old, racc0);
            Mv[j] = __builtin_fmaf(wj, __builtin_fmaf(-e_v, m_old, a_v), m_old);
            outt[j * DD + lane] = Mv[j];           // all 1280 waves store concurrently
        }
        rrow[(size_t)t * DD + lane] = racc0 + racc1;
    }
}

// ---------------- (fallback) K2: chunked scan with dry-run prefix — proven round 7 ----------------
__global__ __launch_bounds__(64) void k2_scan_chunked(
    const float* __restrict__ Mv0,
    const float* __restrict__ w_buf, const float* __restrict__ e_buf,
    const float* __restrict__ a_buf,
    float* __restrict__ read_buf, float* __restrict__ out_Mv)
{
    const int bid  = blockIdx.x;
    const int b    = bid / CHUNKS;
    const int c    = bid % CHUNKS;
    const int lane = threadIdx.x;
    const int t0   = c * CLEN;

    float Mv[MM];
    float* outb = out_Mv + (size_t)b * (SEQ + 1) * MM * DD;
    #pragma unroll
    for (int j = 0; j < MM; ++j)
        Mv[j] = Mv0[j * DD + lane];
    if (c == 0) {
        #pragma unroll
        for (int j = 0; j < MM; ++j)
            outb[j * DD + lane] = Mv[j];
    }

    const float* wrow = w_buf + (size_t)b * SEQ * MM;
    const float* erow = e_buf + (size_t)b * SEQ * DD;
    const float* arow = a_buf + (size_t)b * SEQ * DD;
    float*       rrow = read_buf + (size_t)b * SEQ * DD;

    float wreg = (lane < MM) ? wrow[lane] : 0.f;
    float e_n  = erow[lane];
    float a_n  = arow[lane];

    for (int t = 0; t < t0; ++t) {
        const float e_v = e_n, a_v = a_n, wcur = wreg;
        wreg = (lane < MM) ? wrow[(size_t)(t + 1) * MM + lane] : 0.f;
        e_n  = erow[(size_t)(t + 1) * DD + lane];
        a_n  = arow[(size_t)(t + 1) * DD + lane];
        #pragma unroll
        for (int j = 0; j < MM; ++j) {
            const float wj = rdlane(wcur, j);
            Mv[j] = __builtin_fmaf(wj, __builtin_fmaf(-e_v, Mv[j], a_v), Mv[j]);
        }
    }

    for (int tt = 0; tt < CLEN; ++tt) {
        const int t = t0 + tt;
        const float e_v = e_n, a_v = a_n, wcur = wreg;
        if (t + 1 < SEQ) {
            wreg = (lane < MM) ? wrow[(size_t)(t + 1) * MM + lane] : 0.f;
            e_n  = erow[(size_t)(t + 1) * DD + lane];
            a_n  = arow[(size_t)(t + 1) * DD + lane];
        }
        float* outt = outb + (size_t)(t + 1) * MM * DD;
        float racc0 = 0.f, racc1 = 0.f;
        #pragma unroll
        for (int j = 0; j < MM; ++j) {
            const float wj    = rdlane(wcur, j);
            const float m_old = Mv[j];
            if (j & 1) racc1 = __builtin_fmaf(wj, m_old, racc1);
            else       racc0 = __builtin_fmaf(wj, m_old, racc0);
            Mv[j] = __builtin_fmaf(wj, __builtin_fmaf(-e_v, m_old, a_v), m_old);
            outt[j * DD + lane] = Mv[j];
        }
        rrow[(size_t)t * DD + lane] = racc0 + racc1;
    }
}

// ---------------- K3: f = tanh([read,k]@Wf+bf), p = sigmoid(f.Wp+bp) ----------------
__global__ __launch_bounds__(256) void k3_out(
    const int* __restrict__ q,
    const float* __restrict__ k_emb,
    const float* __restrict__ read_buf,
    const float* __restrict__ Wf, const float* __restrict__ bfb,
    const float* __restrict__ Wp, const float* __restrict__ bp,
    float* __restrict__ out_p)
{
    __shared__ float rk[4][128];
    const int tid  = threadIdx.x;
    const int w    = tid >> 6;
    const int lane = tid & 63;
    const int row  = blockIdx.x * 4 + w;

    int qi = q[row];
    qi = min(max(qi, 0), NUMQ - 1);
    rk[w][lane]      = read_buf[(size_t)row * DD + lane];
    rk[w][64 + lane] = k_emb[(size_t)qi * DD + lane];
    __syncthreads();

    float acc = bfb[lane];
    #pragma unroll
    for (int i = 0; i < 2 * DD; ++i)
        acc = __builtin_fmaf(rk[w][i], Wf[i * DD + lane], acc);
    const float f = tanhf(acc);

    float pv = f * Wp[lane];
    #pragma unroll
    for (int off = 32; off >= 1; off >>= 1)
        pv += __shfl_xor(pv, off, 64);

    if (lane == 0)
        out_p[row] = 1.f / (1.f + expf(-(pv + bp[0])));
}

// ---------------- Last-resort fallback: round-5 fused single kernel (proven, ws-free) ----------------
__global__ __launch_bounds__(640) void dkvmn_fused(
    const int* q_, const int* r_,
    const float* k_emb, const float* v_emb, const float* Mk, const float* Mv0,
    const float* We, const float* be, const float* Wa, const float* ba,
    const float* Wf, const float* bfb, const float* Wp, const float* bp,
    float* out_p, float* out_Mv)
{
    __shared__ float Mk_l[MM][DD + 1];
    __shared__ bf16  ring[SEQ][DD];
    __shared__ int   q_row[SEQ], x_row[SEQ];
    __shared__ float kbuf[DD], vbuf[DD], vbuf2[DD];
    __shared__ float wst[MM], est[DD], ast[DD];
    __shared__ float partial[640];
    __shared__ float bias_e[DD], bias_a[DD];

    const int b    = blockIdx.x;
    const int tid  = threadIdx.x;
    const int wv   = tid >> 6;
    const int lane = tid & 63;

    for (int t = tid; t < SEQ; t += 640) {
        int qi = q_[b * SEQ + t], ri = r_[b * SEQ + t];
        qi = min(max(qi, 0), NUMQ - 1); ri = min(max(ri, 0), 1);
        q_row[t] = qi; x_row[t] = qi + ri * NUMQ;
    }
    for (int i = tid; i < MM * DD; i += 640) Mk_l[i >> 6][i & 63] = Mk[i];
    if (tid < DD) { bias_e[tid] = be[tid]; bias_a[tid] = ba[tid]; }

    const int d  = lane;
    const int m0 = wv * 5;
    float* outb = out_Mv + (size_t)b * (SEQ + 1) * MM * DD;
    float Mv[5];
    #pragma unroll
    for (int j = 0; j < 5; ++j) {
        Mv[j] = Mv0[(m0 + j) * DD + d];
        outb[(m0 + j) * DD + d] = Mv[j];
    }
    __syncthreads();

    float kf_n = 0.f, vf_n = 0.f, vf2_n = 0.f;
    if (wv == 0) kf_n  = k_emb[(size_t)q_row[0] * DD + lane];
    if (wv == 1) vf_n  = v_emb[(size_t)x_row[0] * DD + lane];
    if (wv == 2) vf2_n = v_emb[(size_t)x_row[0] * DD + lane];

    for (int t = 0; t < SEQ; ++t) {
        if (wv == 0) {
            kbuf[lane] = kf_n;
            if (t + 1 < SEQ) kf_n = k_emb[(size_t)q_row[t + 1] * DD + lane];
            float s = 0.f;
            if (lane < MM) {
                #pragma unroll
                for (int dd = 0; dd < DD; ++dd) s += kbuf[dd] * Mk_l[lane][dd];
            }
            float mx = (lane < MM) ? s : -1e30f;
            #pragma unroll
            for (int off = 32; off >= 1; off >>= 1) mx = fmaxf(mx, __shfl_xor(mx, off, 64));
            float ex = (lane < MM) ? expf(s - mx) : 0.f;
            float sm = ex;
            #pragma unroll
            for (int off = 32; off >= 1; off >>= 1) sm += __shfl_xor(sm, off, 64);
            if (lane < MM) wst[lane] = ex / sm;
        } else if (wv == 1) {
            vbuf[lane] = vf_n;
            if (t + 1 < SEQ) vf_n = v_emb[(size_t)x_row[t + 1] * DD + lane];
            float acc = bias_e[lane];
            #pragma unroll
            for (int dd = 0; dd < DD; ++dd) acc += vbuf[dd] * We[dd * DD + lane];
            est[lane] = 1.f / (1.f + expf(-acc));
        } else if (wv == 2) {
            vbuf2[lane] = vf2_n;
            if (t + 1 < SEQ) vf2_n = v_emb[(size_t)x_row[t + 1] * DD + lane];
            float acc = bias_a[lane];
            #pragma unroll
            for (int dd = 0; dd < DD; ++dd) acc += vbuf2[dd] * Wa[dd * DD + lane];
            ast[lane] = tanhf(acc);
        }
        __syncthreads();

        const float e_v = est[d];
        const float a_v = ast[d];
        float racc = 0.f;
        float* outt = outb + (size_t)(t + 1) * MM * DD;
        #pragma unroll
        for (int j = 0; j < 5; ++j) {
            const float wvv = wst[m0 + j];
            racc += wvv * Mv[j];
            Mv[j] = __builtin_fmaf(wvv, a_v - e_v * Mv[j], Mv[j]);
            outt[(m0 + j) * DD + d] = Mv[j];
        }
        partial[tid] = racc;
        __syncthreads();

        if (tid < DD) {
            float rr = 0.f;
            #pragma unroll
            for (int g = 0; g < 10; ++g) rr += partial[g * 64 + tid];
            ring[t][tid] = (bf16)rr;
        }
    }
    __syncthreads();

    for (int t = wv; t < SEQ; t += 10) {
        const int qi = q_row[t];
        const float kreg = k_emb[(size_t)qi * DD + lane];
        float acc = bfb[lane];
        #pragma unroll
        for (int i = 0; i < DD; ++i) acc += (float)ring[t][i] * Wf[i * DD + lane];
        #pragma unroll
        for (int i = 0; i < DD; ++i) acc += __shfl(kreg, i, 64) * Wf[(DD + i) * DD + lane];
        const float f = tanhf(acc);
        float pv = f * Wp[lane];
        #pragma unroll
        for (int off = 32; off >= 1; off >>= 1) pv += __shfl_xor(pv, off, 64);
        if (lane == 0)
            out_p[(size_t)b * SEQ + t] = 1.f / (1.f + expf(-(pv + bp[0])));
    }
}

extern "C" void kernel_launch(void* const* d_in, const int* in_sizes, int n_in,
                              void* d_out, int out_size, void* d_ws, size_t ws_size,
                              hipStream_t stream) {
    const int*   q     = (const int*)  d_in[0];
    const int*   r     = (const int*)  d_in[1];
    const float* k_emb = (const float*)d_in[4];
    const float* v_emb = (const float*)d_in[5];
    const float* Mk    = (const float*)d_in[6];
    const float* Mv0   = (const float*)d_in[7];
    const float* We    = (const float*)d_in[8];
    const float* be    = (const float*)d_in[9];
    const float* Wa    = (const float*)d_in[10];
    const float* ba    = (const float*)d_in[11];
    const float* Wf    = (const float*)d_in[12];
    const float* bfb   = (const float*)d_in[13];
    const float* Wp    = (const float*)d_in[14];
    const float* bp    = (const float*)d_in[15];

    float* out_p  = (float*)d_out;                 // [128,200]
    float* out_Mv = (float*)d_out + BATCH * SEQ;   // [128,201,50,64]

    const size_t N_WEA  = (size_t)BATCH * SEQ * (MM + 3 * DD);        // w,e,a,read
    const size_t N_SUM  = (size_t)BATCH * CHUNKS * MM * DD;           // per A or B
    const size_t WS_BASE = N_WEA * sizeof(float);                     // 24.8 MB
    const size_t WS_HIER = WS_BASE + 2 * N_SUM * sizeof(float);       // 57.5 MB

    const int rows = BATCH * SEQ;

    if (ws_size >= WS_BASE) {
        float* w_buf    = (float*)d_ws;                          // [B,SEQ,50]
        float* e_buf    = w_buf + (size_t)BATCH * SEQ * MM;      // [B,SEQ,64]
        float* a_buf    = e_buf + (size_t)BATCH * SEQ * DD;      // [B,SEQ,64]
        float* read_buf = a_buf + (size_t)BATCH * SEQ * DD;      // [B,SEQ,64]

        hipLaunchKernelGGL(k1_precompute, dim3(rows / 4), dim3(256), 0, stream,
                           q, r, k_emb, v_emb, Mk, We, be, Wa, ba, w_buf, e_buf, a_buf);

        if (ws_size >= WS_HIER) {
            float* Abuf = read_buf + (size_t)BATCH * SEQ * DD;   // [B,CHUNKS,50,64]
            float* Bbuf = Abuf + N_SUM;                          // [B,CHUNKS,50,64]
            hipLaunchKernelGGL(k2a_summary, dim3(BATCH * CHUNKS), dim3(64), 0, stream,
                               w_buf, e_buf, a_buf, Abuf, Bbuf);
            hipLaunchKernelGGL(k2c_replay, dim3(BATCH * CHUNKS), dim3(64), 0, stream,
                               Mv0, w_buf, e_buf, a_buf, Abuf, Bbuf, read_buf, out_Mv);
        } else {
            hipLaunchKernelGGL(k2_scan_chunked, dim3(BATCH * CHUNKS), dim3(64), 0, stream,
                               Mv0, w_buf, e_buf, a_buf, read_buf, out_Mv);
        }

        hipLaunchKernelGGL(k3_out, dim3(rows / 4), dim3(256), 0, stream,
                           q, k_emb, read_buf, Wf, bfb, Wp, bp, out_p);
    } else {
        hipLaunchKernelGGL(dkvmn_fused, dim3(BATCH), dim3(640), 0, stream,
                           q, r, k_emb, v_emb, Mk, Mv0, We, be, Wa, ba,
                           Wf, bfb, Wp, bp, out_p, out_Mv);
    }
}